// Round 4
// baseline (121.888 us; speedup 1.0000x reference)
//
#include <hip/hip_runtime.h>

#define HW (512 * 512)          // elements per (batch, channel) row
#define BATCH 64
#define NROWS (BATCH * 3)       // 192
#define NB 100
#define NCOPY 16                // LDS sub-histogram copies per block
#define CSTRIDE 101             // copy stride -> 16 distinct banks across copies
#define HIST_CHUNKS 16          // blocks per row in hist pass
#define NORM_CHUNKS 32          // blocks per row in normalize pass
#define NHALF 2
#define HALF_B (BATCH / NHALF)          // 32 images per half
#define HALF_ROWS (HALF_B * 3)          // 96 rows per half

typedef float f32x4 __attribute__((ext_vector_type(4)));  // native vec for nontemporal builtin

// ---------------- Pass 1: per-(row,chunk) partial 100-bin histogram ----------------
__global__ __launch_bounds__(256) void hist_kernel(const float* __restrict__ lab,
                                                   unsigned int* __restrict__ part,
                                                   int row0) {
    __shared__ unsigned int sh[NCOPY * CSTRIDE];
    for (int i = threadIdx.x; i < NCOPY * CSTRIDE; i += 256) sh[i] = 0;
    __syncthreads();

    const int row   = row0 + blockIdx.x / HIST_CHUNKS;   // global b*3 + c
    const int chunk = blockIdx.x % HIST_CHUNKS;
    const int c     = row % 3;

    // histc parameters (match reference float32 math exactly)
    const float lo = (c == 0) ? 0.0f   : -128.0f;
    const float hi = (c == 0) ? 100.0f : 127.0f;
    const float bs = (c == 0) ? 1.0f   : 2.55f;

    unsigned int* wh = &sh[(threadIdx.x & (NCOPY - 1)) * CSTRIDE];

    const int n4 = HW / 4 / HIST_CHUNKS;          // 4096 float4 per block
    const f32x4* p = (const f32x4*)(lab + (size_t)row * HW) + (size_t)chunk * n4;

    for (int i = threadIdx.x; i < n4; i += 256) {
        f32x4 v = p[i];
#pragma unroll
        for (int k = 0; k < 4; ++k) {
            float x = v[k];
            if (x >= lo && x <= hi) {                   // histc: outside range ignored
                int idx = (int)floorf((x - lo) / bs);   // f32 true division (bit-exact vs ref)
                idx = idx > (NB - 1) ? (NB - 1) : idx;  // x == hi -> last bin
                atomicAdd(&wh[idx], 1u);
            }
        }
    }
    __syncthreads();

    for (int i = threadIdx.x; i < NB; i += 256) {
        unsigned int s = 0;
#pragma unroll
        for (int j = 0; j < NCOPY; ++j) s += sh[j * CSTRIDE + i];
        part[((size_t)row * HIST_CHUNKS + chunk) * NB + i] = s;   // plain store, no memset
    }
}

// ---------------- Pass 2: reduce partials, find peaks, emit affine coeffs ----------------
// L: second peak (top_k tie-break: lower index first);  A/B: argmax (first occurrence)
__global__ __launch_bounds__(128) void peaks_kernel(const unsigned int* __restrict__ part,
                                                    const float* __restrict__ ref_l,
                                                    const float* __restrict__ ref_a,
                                                    const float* __restrict__ ref_b,
                                                    float* __restrict__ coeffs,
                                                    int b0) {
    __shared__ unsigned int hh[3][NB];
    const int b = b0 + blockIdx.x;
    for (int c = 0; c < 3; ++c) {
        if (threadIdx.x < NB) {
            unsigned int s = 0;
            const unsigned int* p = part + (size_t)(b * 3 + c) * HIST_CHUNKS * NB + threadIdx.x;
            for (int k = 0; k < HIST_CHUNKS; ++k) s += p[(size_t)k * NB];  // coalesced across bins
            hh[c][threadIdx.x] = s;
        }
    }
    __syncthreads();

    if (threadIdx.x == 0) {
        // L channel: second-highest bin, jax top_k tie-break semantics.
        long best = -1, sec = -1; int bi = 0, si = 0;
        for (int i = 0; i < NB; ++i) {
            long cnt = (long)hh[0][i];
            if (cnt > best)     { sec = best; si = bi; best = cnt; bi = i; }
            else if (cnt > sec) { sec = cnt;  si = i; }
        }
        float pL = (si + 0.5f);                       // lo = 0, bin = 1
        coeffs[b * 6 + 0] = ref_l[0] / pL * (1.0f / 200.0f);
        coeffs[b * 6 + 1] = 0.5f;
    } else if (threadIdx.x == 1 || threadIdx.x == 2) {
        int c = threadIdx.x;
        long best = -1; int bi = 0;
        for (int i = 0; i < NB; ++i) {
            long cnt = (long)hh[c][i];
            if (cnt > best) { best = cnt; bi = i; }
        }
        float p = -128.0f + (bi + 0.5f) * 2.55f;
        float r = (c == 1) ? ref_a[0] : ref_b[0];
        coeffs[b * 6 + c * 2]     = r / p * (1.0f / 255.0f);
        coeffs[b * 6 + c * 2 + 1] = 128.0f / 255.0f;
    }
}

// ---------------- Pass 3: elementwise affine; reads should hit L3, nt stores ----------------
__global__ __launch_bounds__(256) void norm_kernel(const float* __restrict__ lab,
                                                   const float* __restrict__ coeffs,
                                                   float* __restrict__ out,
                                                   int row0) {
    const int row   = row0 + blockIdx.x / NORM_CHUNKS;
    const int chunk = blockIdx.x % NORM_CHUNKS;
    const float s = coeffs[row * 2];
    const float o = coeffs[row * 2 + 1];

    const int n4 = HW / 4 / NORM_CHUNKS;           // 2048
    const size_t base = (size_t)row * (HW / 4) + (size_t)chunk * n4;
    const f32x4* ip = (const f32x4*)lab + base;
    f32x4*       op = (f32x4*)out + base;

    for (int i = threadIdx.x; i < n4; i += 256) {
        f32x4 v = ip[i];
        v.x = fmaf(v.x, s, o);
        v.y = fmaf(v.y, s, o);
        v.z = fmaf(v.z, s, o);
        v.w = fmaf(v.w, s, o);
        __builtin_nontemporal_store(v, &op[i]);    // don't let out evict lab from L3
    }
}

extern "C" void kernel_launch(void* const* d_in, const int* in_sizes, int n_in,
                              void* d_out, int out_size, void* d_ws, size_t ws_size,
                              hipStream_t stream) {
    const float* lab   = (const float*)d_in[0];
    const float* ref_l = (const float*)d_in[1];
    const float* ref_a = (const float*)d_in[2];
    const float* ref_b = (const float*)d_in[3];
    float* out = (float*)d_out;

    const size_t part_bytes = (size_t)NROWS * HIST_CHUNKS * NB * sizeof(unsigned int); // 1.23 MB
    unsigned int* part = (unsigned int*)d_ws;
    float* coeffs = (float*)((char*)d_ws + part_bytes);

    // Temporal blocking: per half, {lab-half + out-half} = 200 MB fits the 256 MB L3,
    // so norm's re-read of lab is an L3 hit instead of a second HBM read.
    for (int h = 0; h < NHALF; ++h) {
        const int row0 = h * HALF_ROWS;
        const int b0   = h * HALF_B;
        hipLaunchKernelGGL(hist_kernel, dim3(HALF_ROWS * HIST_CHUNKS), dim3(256), 0, stream,
                           lab, part, row0);
        hipLaunchKernelGGL(peaks_kernel, dim3(HALF_B), dim3(128), 0, stream,
                           part, ref_l, ref_a, ref_b, coeffs, b0);
        hipLaunchKernelGGL(norm_kernel, dim3(HALF_ROWS * NORM_CHUNKS), dim3(256), 0, stream,
                           lab, coeffs, out, row0);
    }
}

// Round 5
// 120.544 us; speedup vs baseline: 1.0111x; 1.0111x over previous
//
#include <hip/hip_runtime.h>

#define HW (512 * 512)          // elements per (batch, channel) row
#define BATCH 64
#define NROWS (BATCH * 3)       // 192
#define NB 100
#define NCOPY 16                // LDS sub-histogram copies per block
#define CSTRIDE 101             // copy stride -> 16 distinct banks across copies
#define HIST_CHUNKS 16          // blocks per row in hist pass
#define NORM_CHUNKS 32          // blocks per row in normalize pass

typedef float f32x4 __attribute__((ext_vector_type(4)));

// ---------------- Pass 1: per-(row,chunk) partial 100-bin histogram ----------------
__global__ __launch_bounds__(256) void hist_kernel(const float* __restrict__ lab,
                                                   unsigned int* __restrict__ part) {
    __shared__ unsigned int sh[NCOPY * CSTRIDE];
    for (int i = threadIdx.x; i < NCOPY * CSTRIDE; i += 256) sh[i] = 0;
    __syncthreads();

    const int row   = blockIdx.x / HIST_CHUNKS;   // b*3 + c
    const int chunk = blockIdx.x % HIST_CHUNKS;
    const int c     = row % 3;

    // histc parameters (match reference float32 math exactly)
    const float lo = (c == 0) ? 0.0f   : -128.0f;
    const float hi = (c == 0) ? 100.0f : 127.0f;
    const float bs = (c == 0) ? 1.0f   : 2.55f;

    unsigned int* wh = &sh[(threadIdx.x & (NCOPY - 1)) * CSTRIDE];

    const int n4 = HW / 4 / HIST_CHUNKS;          // 4096 float4 per block
    const f32x4* p = (const f32x4*)(lab + (size_t)row * HW) + (size_t)chunk * n4;

    for (int i = threadIdx.x; i < n4; i += 256) {
        f32x4 v = p[i];
#pragma unroll
        for (int k = 0; k < 4; ++k) {
            float x = v[k];
            if (x >= lo && x <= hi) {                   // histc: outside range ignored
                int idx = (int)floorf((x - lo) / bs);   // f32 true division (bit-exact vs ref)
                idx = idx > (NB - 1) ? (NB - 1) : idx;  // x == hi -> last bin
                atomicAdd(&wh[idx], 1u);
            }
        }
    }
    __syncthreads();

    for (int i = threadIdx.x; i < NB; i += 256) {
        unsigned int s = 0;
#pragma unroll
        for (int j = 0; j < NCOPY; ++j) s += sh[j * CSTRIDE + i];
        part[((size_t)row * HIST_CHUNKS + chunk) * NB + i] = s;   // plain store, no memset
    }
}

// ---------------- Pass 2: reduce partials, find peaks, emit affine coeffs ----------------
// L: second peak (top_k tie-break: lower index first);  A/B: argmax (first occurrence)
__global__ __launch_bounds__(128) void peaks_kernel(const unsigned int* __restrict__ part,
                                                    const float* __restrict__ ref_l,
                                                    const float* __restrict__ ref_a,
                                                    const float* __restrict__ ref_b,
                                                    float* __restrict__ coeffs) {
    __shared__ unsigned int hh[3][NB];
    const int b = blockIdx.x;
    for (int c = 0; c < 3; ++c) {
        if (threadIdx.x < NB) {
            unsigned int s = 0;
            const unsigned int* p = part + (size_t)(b * 3 + c) * HIST_CHUNKS * NB + threadIdx.x;
            for (int k = 0; k < HIST_CHUNKS; ++k) s += p[(size_t)k * NB];  // coalesced across bins
            hh[c][threadIdx.x] = s;
        }
    }
    __syncthreads();

    if (threadIdx.x == 0) {
        long best = -1, sec = -1; int bi = 0, si = 0;
        for (int i = 0; i < NB; ++i) {
            long cnt = (long)hh[0][i];
            if (cnt > best)     { sec = best; si = bi; best = cnt; bi = i; }
            else if (cnt > sec) { sec = cnt;  si = i; }
        }
        float pL = (si + 0.5f);                       // lo = 0, bin = 1
        coeffs[b * 6 + 0] = ref_l[0] / pL * (1.0f / 200.0f);
        coeffs[b * 6 + 1] = 0.5f;
    } else if (threadIdx.x == 1 || threadIdx.x == 2) {
        int c = threadIdx.x;
        long best = -1; int bi = 0;
        for (int i = 0; i < NB; ++i) {
            long cnt = (long)hh[c][i];
            if (cnt > best) { best = cnt; bi = i; }
        }
        float p = -128.0f + (bi + 0.5f) * 2.55f;
        float r = (c == 1) ? ref_a[0] : ref_b[0];
        coeffs[b * 6 + c * 2]     = r / p * (1.0f / 255.0f);
        coeffs[b * 6 + c * 2 + 1] = 128.0f / 255.0f;
    }
}

// ---------------- Pass 3: elementwise affine, PLAIN stores (A/B vs R3's nt) ----------------
__global__ __launch_bounds__(256) void norm_kernel(const float* __restrict__ lab,
                                                   const float* __restrict__ coeffs,
                                                   float* __restrict__ out) {
    const int row   = blockIdx.x / NORM_CHUNKS;
    const int chunk = blockIdx.x % NORM_CHUNKS;
    const float s = coeffs[row * 2];
    const float o = coeffs[row * 2 + 1];

    const int n4 = HW / 4 / NORM_CHUNKS;           // 2048
    const size_t base = (size_t)row * (HW / 4) + (size_t)chunk * n4;
    const f32x4* ip = (const f32x4*)lab + base;
    f32x4*       op = (f32x4*)out + base;

    for (int i = threadIdx.x; i < n4; i += 256) {
        f32x4 v = ip[i];
        v.x = fmaf(v.x, s, o);
        v.y = fmaf(v.y, s, o);
        v.z = fmaf(v.z, s, o);
        v.w = fmaf(v.w, s, o);
        op[i] = v;                                  // plain store (write-allocate path)
    }
}

extern "C" void kernel_launch(void* const* d_in, const int* in_sizes, int n_in,
                              void* d_out, int out_size, void* d_ws, size_t ws_size,
                              hipStream_t stream) {
    const float* lab   = (const float*)d_in[0];
    const float* ref_l = (const float*)d_in[1];
    const float* ref_a = (const float*)d_in[2];
    const float* ref_b = (const float*)d_in[3];
    float* out = (float*)d_out;

    const size_t part_bytes = (size_t)NROWS * HIST_CHUNKS * NB * sizeof(unsigned int); // 1.23 MB
    unsigned int* part = (unsigned int*)d_ws;
    float* coeffs = (float*)((char*)d_ws + part_bytes);

    hipLaunchKernelGGL(hist_kernel, dim3(NROWS * HIST_CHUNKS), dim3(256), 0, stream,
                       lab, part);
    hipLaunchKernelGGL(peaks_kernel, dim3(BATCH), dim3(128), 0, stream,
                       part, ref_l, ref_a, ref_b, coeffs);
    hipLaunchKernelGGL(norm_kernel, dim3(NROWS * NORM_CHUNKS), dim3(256), 0, stream,
                       lab, coeffs, out);
}

// Round 7
// 100.468 us; speedup vs baseline: 1.2132x; 1.1998x over previous
//
#include <hip/hip_runtime.h>

#define HW (512 * 512)          // elements per (batch, channel) row
#define BATCH 64
#define NROWS (BATCH * 3)       // 192
#define NB 100
#define NCOPY 16                // LDS sub-histogram copies per block
#define CSTRIDE 101             // copy stride -> 16 distinct banks across copies
#define HIST_CHUNKS 16          // blocks per row in hist pass
#define NORM_CHUNKS 32          // blocks per row in normalize pass

typedef float f32x4 __attribute__((ext_vector_type(4)));

// ---------------- Pass 1: per-(row,chunk) partial 100-bin histogram ----------------
__global__ __launch_bounds__(256) void hist_kernel(const float* __restrict__ lab,
                                                   unsigned int* __restrict__ part) {
    __shared__ unsigned int sh[NCOPY * CSTRIDE];
    for (int i = threadIdx.x; i < NCOPY * CSTRIDE; i += 256) sh[i] = 0;
    __syncthreads();

    const int row   = blockIdx.x / HIST_CHUNKS;   // b*3 + c
    const int chunk = blockIdx.x % HIST_CHUNKS;
    const int c     = row % 3;

    // histc parameters (match reference float32 math exactly)
    const float lo = (c == 0) ? 0.0f   : -128.0f;
    const float hi = (c == 0) ? 100.0f : 127.0f;
    const float bs = (c == 0) ? 1.0f   : 2.55f;

    unsigned int* wh = &sh[(threadIdx.x & (NCOPY - 1)) * CSTRIDE];

    const int n4 = HW / 4 / HIST_CHUNKS;          // 4096 float4 per block
    const f32x4* p = (const f32x4*)(lab + (size_t)row * HW) + (size_t)chunk * n4;

    for (int i = threadIdx.x; i < n4; i += 256) {
        f32x4 v = p[i];
#pragma unroll
        for (int k = 0; k < 4; ++k) {
            float x = v[k];
            if (x >= lo && x <= hi) {                   // histc: outside range ignored
                int idx = (int)floorf((x - lo) / bs);   // f32 true division (bit-exact vs ref)
                idx = idx > (NB - 1) ? (NB - 1) : idx;  // x == hi -> last bin
                atomicAdd(&wh[idx], 1u);
            }
        }
    }
    __syncthreads();

    for (int i = threadIdx.x; i < NB; i += 256) {
        unsigned int s = 0;
#pragma unroll
        for (int j = 0; j < NCOPY; ++j) s += sh[j * CSTRIDE + i];
        part[((size_t)row * HIST_CHUNKS + chunk) * NB + i] = s;   // plain store, no memset
    }
}

// ---------------- Pass 2: fused peaks + affine normalize ----------------
// Each block re-derives its OWN row's (scale, offset) from the partials
// (6.4 KB L2-resident reads + ~100-iter scan), then streams its chunk.
// L rows: second peak (jax top_k tie-break: lower index first).
// A/B rows: argmax (first occurrence).
__global__ __launch_bounds__(256) void norm_kernel(const float* __restrict__ lab,
                                                   const unsigned int* __restrict__ part,
                                                   const float* __restrict__ ref_l,
                                                   const float* __restrict__ ref_a,
                                                   const float* __restrict__ ref_b,
                                                   float* __restrict__ out) {
    __shared__ unsigned int hh[NB];
    __shared__ float so[2];

    const int row   = blockIdx.x / NORM_CHUNKS;   // b*3 + c
    const int chunk = blockIdx.x % NORM_CHUNKS;
    const int c     = row % 3;

    // Reduce this row's partial histograms (coalesced across bins).
    if (threadIdx.x < NB) {
        unsigned int s = 0;
        const unsigned int* p = part + (size_t)row * HIST_CHUNKS * NB + threadIdx.x;
#pragma unroll
        for (int k = 0; k < HIST_CHUNKS; ++k) s += p[(size_t)k * NB];
        hh[threadIdx.x] = s;
    }
    __syncthreads();

    if (threadIdx.x == 0) {
        if (c == 0) {
            // L: second-highest bin.
            long best = -1, sec = -1; int bi = 0, si = 0;
            for (int i = 0; i < NB; ++i) {
                long cnt = (long)hh[i];
                if (cnt > best)     { sec = best; si = bi; best = cnt; bi = i; }
                else if (cnt > sec) { sec = cnt;  si = i; }
            }
            float pL = (si + 0.5f);                  // lo = 0, bin = 1
            so[0] = ref_l[0] / pL * (1.0f / 200.0f);
            so[1] = 0.5f;
        } else {
            long best = -1; int bi = 0;
            for (int i = 0; i < NB; ++i) {
                long cnt = (long)hh[i];
                if (cnt > best) { best = cnt; bi = i; }
            }
            float p = -128.0f + (bi + 0.5f) * 2.55f;
            float r = (c == 1) ? ref_a[0] : ref_b[0];
            so[0] = r / p * (1.0f / 255.0f);
            so[1] = 128.0f / 255.0f;
        }
    }
    __syncthreads();

    const float s = so[0];
    const float o = so[1];

    const int n4 = HW / 4 / NORM_CHUNKS;           // 2048
    const size_t base = (size_t)row * (HW / 4) + (size_t)chunk * n4;
    const f32x4* ip = (const f32x4*)lab + base;
    f32x4*       op = (f32x4*)out + base;

    for (int i = threadIdx.x; i < n4; i += 256) {
        f32x4 v = ip[i];
        v.x = fmaf(v.x, s, o);
        v.y = fmaf(v.y, s, o);
        v.z = fmaf(v.z, s, o);
        v.w = fmaf(v.w, s, o);
        __builtin_nontemporal_store(v, &op[i]);    // nt: proven +9 us (R3 vs R5 A/B)
    }
}

extern "C" void kernel_launch(void* const* d_in, const int* in_sizes, int n_in,
                              void* d_out, int out_size, void* d_ws, size_t ws_size,
                              hipStream_t stream) {
    const float* lab   = (const float*)d_in[0];
    const float* ref_l = (const float*)d_in[1];
    const float* ref_a = (const float*)d_in[2];
    const float* ref_b = (const float*)d_in[3];
    float* out = (float*)d_out;

    unsigned int* part = (unsigned int*)d_ws;      // NROWS*HIST_CHUNKS*NB u32 = 1.23 MB

    hipLaunchKernelGGL(hist_kernel, dim3(NROWS * HIST_CHUNKS), dim3(256), 0, stream,
                       lab, part);
    hipLaunchKernelGGL(norm_kernel, dim3(NROWS * NORM_CHUNKS), dim3(256), 0, stream,
                       lab, part, ref_l, ref_a, ref_b, out);
}